// Round 11
// baseline (158.730 us; speedup 1.0000x reference)
//
#include <hip/hip_runtime.h>
#include <hip/hip_bf16.h>

#define N_NODES 8192
#define N_EDGES 262144
#define F_INDIM 128
#define HID 256
#define F_OUT 128
#define N_GRAPHS 64
#define WPR (N_NODES / 32)   // 256 words per bitmask row
#define CAP 160              // max supported degree (Poisson(64), 12 sigma headroom)
#define NQ 32                // wpool j-chunks

struct alignas(8) bf4 { __hip_bfloat16 a, b, c, d; };

__device__ inline float2 bf2unpack(unsigned int u) {
    float2 r;
    r.x = __uint_as_float(u << 16);          // low ushort  -> col 2l
    r.y = __uint_as_float(u & 0xffff0000u);  // high ushort -> col 2l+1
    return r;
}

// ---------------------------------------------------------------------------
// 1. cast X -> bf16 (blocks 0..1023) and zero mask (blocks 1024..3071)
// ---------------------------------------------------------------------------
__global__ __launch_bounds__(256) void cast_zero(const float* __restrict__ X,
                                                 __hip_bfloat16* __restrict__ Xh,
                                                 unsigned int* __restrict__ mask) {
    int b = blockIdx.x, t = threadIdx.x;
    if (b < 1024) {                       // 1024*256 = N*F/4 float4 casts
        int i = b * 256 + t;
        float4 v = ((const float4*)X)[i];
        bf4 o;
        o.a = __float2bfloat16(v.x); o.b = __float2bfloat16(v.y);
        o.c = __float2bfloat16(v.z); o.d = __float2bfloat16(v.w);
        ((bf4*)Xh)[i] = o;
    } else {                              // 2048*256 = 8MB/16B uint4 zeros
        int i = (b - 1024) * 256 + t;
        uint4 z = {0u, 0u, 0u, 0u};
        ((uint4*)mask)[i] = z;
    }
}

// ---------------------------------------------------------------------------
// 2. Edge scatter, 2 edges per thread (int2 loads)  [R2-proven atomics]
// ---------------------------------------------------------------------------
__global__ __launch_bounds__(256) void scatter_edges(const int* __restrict__ ei,
                                                     unsigned int* __restrict__ mask) {
    int e2 = blockIdx.x * 256 + threadIdx.x;   // covers edges 2*e2, 2*e2+1
    int2 s2 = ((const int2*)ei)[e2];
    int2 d2 = ((const int2*)(ei + N_EDGES))[e2];
    if ((unsigned)s2.x < N_NODES && (unsigned)d2.x < N_NODES) {
        atomicOr(&mask[(size_t)s2.x * WPR + (d2.x >> 5)], 1u << (d2.x & 31));
        atomicOr(&mask[(size_t)d2.x * WPR + (s2.x >> 5)], 1u << (s2.x & 31));
    }
    if ((unsigned)s2.y < N_NODES && (unsigned)d2.y < N_NODES) {
        atomicOr(&mask[(size_t)s2.y * WPR + (d2.y >> 5)], 1u << (d2.y & 31));
        atomicOr(&mask[(size_t)d2.y * WPR + (s2.y >> 5)], 1u << (s2.y & 31));
    }
}

// ---------------------------------------------------------------------------
// 3. compute_dis: wave per row, popcount -> dis = rsqrt(deg+1)
// ---------------------------------------------------------------------------
__global__ __launch_bounds__(256) void compute_dis(const unsigned int* __restrict__ mask,
                                                   float* __restrict__ dis) {
    int row = (blockIdx.x * blockDim.x + threadIdx.x) >> 6;
    int lane = threadIdx.x & 63;
    uint4 v = ((const uint4*)(mask + (size_t)row * WPR))[lane];
    int c = __popc(v.x) + __popc(v.y) + __popc(v.z) + __popc(v.w);
    for (int off = 32; off; off >>= 1) c += __shfl_down(c, off);
    if (lane == 0) dis[row] = rsqrtf((float)(c + 1));  // +1: identity
}

// ---------------------------------------------------------------------------
// 4. spmm_scan2: TWO waves per row. Wave half=0 scans the mask row into an
//    LDS neighbor list; both waves gather disjoint halves (chain length d/2);
//    partials combined in LDS. Outputs G, sv, u as before.
// ---------------------------------------------------------------------------
__global__ __launch_bounds__(256) void spmm_scan2(const unsigned int* __restrict__ mask,
                                                  const __hip_bfloat16* __restrict__ Xh,
                                                  const float* __restrict__ dis,
                                                  const int* __restrict__ batch,
                                                  float* __restrict__ G,
                                                  float* __restrict__ sv,
                                                  float* __restrict__ u) {
    int w = threadIdx.x >> 6, lane = threadIdx.x & 63;
    int r = w >> 1;           // local row 0..1
    int half = w & 1;         // which half of the neighbor list
    int i = blockIdx.x * 2 + r;
    __shared__ int    nb[2][CAP];
    __shared__ float  nbd[2][CAP];
    __shared__ float  ul[2][64];
    __shared__ int    dsh[2];
    __shared__ float  psh[2][2];
    __shared__ float2 gpart[2][64];

    if (half == 1) ul[r][lane] = 0.0f;
    if (half == 0) {
        uint4 v = ((const uint4*)(mask + (size_t)i * WPR))[lane];
        int cnt = __popc(v.x) + __popc(v.y) + __popc(v.z) + __popc(v.w);
        int scan = cnt;
        for (int off = 1; off < 64; off <<= 1) {
            int n = __shfl_up(scan, off);
            if (lane >= off) scan += n;
        }
        int tot = __shfl(scan, 63);
        int idx = scan - cnt;
        int wbase = lane << 7;
        unsigned int wd;
        wd = v.x; while (wd) { int b = __ffs(wd) - 1; wd &= wd - 1; if (idx < CAP) nb[r][idx] = wbase + b;      ++idx; }
        wd = v.y; while (wd) { int b = __ffs(wd) - 1; wd &= wd - 1; if (idx < CAP) nb[r][idx] = wbase + 32 + b; ++idx; }
        wd = v.z; while (wd) { int b = __ffs(wd) - 1; wd &= wd - 1; if (idx < CAP) nb[r][idx] = wbase + 64 + b; ++idx; }
        wd = v.w; while (wd) { int b = __ffs(wd) - 1; wd &= wd - 1; if (idx < CAP) nb[r][idx] = wbase + 96 + b; ++idx; }
        if (lane == 0) dsh[r] = (tot > CAP) ? CAP : tot;
    }
    __syncthreads();           // nb, dsh, ul-zero visible
    int d  = dsh[r];
    int d0 = d >> 1;
    int lo = half ? d0 : 0;
    int hi = half ? d  : d0;
    float di = dis[i];
    // phase 2a: nbd fill + sv partial + u histogram over my range
    float p = 0.0f;
    for (int t = lo + lane; t < hi; t += 64) {
        int j = nb[r][t];
        float dj = dis[j];
        nbd[r][t] = dj;
        p += dj;
        atomicAdd(&ul[r][batch[j] & 63], dj);
    }
    if (half == 0 && lane == 0) atomicAdd(&ul[r][batch[i] & 63], di);  // +I diag
    for (int off = 32; off; off >>= 1) p += __shfl_down(p, off);
    if (lane == 0) psh[r][half] = p;
    __syncthreads();           // nbd, psh, ul complete
    const unsigned int* Xu = (const unsigned int*)Xh;  // row stride 64 uints
    float2 a0 = {0,0}, a1 = {0,0}, a2 = {0,0}, a3 = {0,0},
           a4 = {0,0}, a5 = {0,0}, a6 = {0,0}, a7 = {0,0};
    if (half == 0) {           // identity term
        float2 xi = bf2unpack(Xu[(size_t)i * 64 + lane]);
        a0.x = di * xi.x; a0.y = di * xi.y;
    }
    int k = lo;
    for (; k + 8 <= hi; k += 8) {
#define GATH(Q, ACC) { int j = nb[r][k+Q]; float dj = nbd[r][k+Q]; \
        float2 f = bf2unpack(Xu[(size_t)j * 64 + lane]); \
        ACC.x += dj * f.x; ACC.y += dj * f.y; }
        GATH(0, a0) GATH(1, a1) GATH(2, a2) GATH(3, a3)
        GATH(4, a4) GATH(5, a5) GATH(6, a6) GATH(7, a7)
    }
    for (; k < hi; ++k) GATH(0, a0)
#undef GATH
    float2 s;
    s.x = ((a0.x + a1.x) + (a2.x + a3.x)) + ((a4.x + a5.x) + (a6.x + a7.x));
    s.y = ((a0.y + a1.y) + (a2.y + a3.y)) + ((a4.y + a5.y) + (a6.y + a7.y));
    if (half == 1) gpart[r][lane] = s;
    __syncthreads();           // gpart visible
    if (half == 0) {
        float2 o = gpart[r][lane];
        o.x = di * (s.x + o.x);
        o.y = di * (s.y + o.y);
        ((float2*)(G + (size_t)i * F_INDIM))[lane] = o;
        if (lane == 0) sv[i] = di * (di + psh[r][0] + psh[r][1]);
        u[(size_t)i * N_GRAPHS + lane] = ul[r][lane];  // coalesced 256B per wave
    }
}

// ---------------------------------------------------------------------------
// 5. fused_gemm  [R8 proven body] + block 0 zeroes `out` for wpool atomics
// ---------------------------------------------------------------------------
__global__ __launch_bounds__(256) void fused_gemm(const float* __restrict__ G,
                                                  const float* __restrict__ W1,
                                                  const float* __restrict__ b1,
                                                  const float* __restrict__ sv,
                                                  const float* __restrict__ W2,
                                                  const float* __restrict__ b2,
                                                  const float* __restrict__ dis,
                                                  __hip_bfloat16* __restrict__ M2ph,
                                                  float* __restrict__ out) {
    int i0 = blockIdx.x * 16;
    int t = threadIdx.x;
    if (blockIdx.x == 0) {   // zero out (64x128 f32 = 2048 float4)
        float4 z = {0,0,0,0};
        for (int v = t; v < N_GRAPHS * F_OUT / 4; v += 256) ((float4*)out)[v] = z;
    }
    __shared__ float xs[16][F_INDIM];   // 8 KB
    __shared__ float hs[16][HID];       // 16 KB
    for (int v = t; v < 16 * F_INDIM / 4; v += 256) {
        int r = v >> 5, c4 = (v & 31) << 2;
        *(float4*)&xs[r][c4] = *(const float4*)&G[(size_t)(i0 + r) * F_INDIM + c4];
    }
    __syncthreads();
    // ---- stage 1: 4 rows x 4 cols per thread over K=128 ----
    {
        int tc = t & 63, tr = t >> 6;
        float4 acc0 = {0,0,0,0}, acc1 = {0,0,0,0}, acc2 = {0,0,0,0}, acc3 = {0,0,0,0};
        const float* wp = W1 + 4 * tc;
        for (int k = 0; k < F_INDIM; k += 4) {
            float4 w0 = *(const float4*)&wp[(size_t)(k + 0) * HID];
            float4 w1 = *(const float4*)&wp[(size_t)(k + 1) * HID];
            float4 w2 = *(const float4*)&wp[(size_t)(k + 2) * HID];
            float4 w3 = *(const float4*)&wp[(size_t)(k + 3) * HID];
#define ROW(R, ACC) { \
            float4 g4 = *(const float4*)&xs[4 * tr + R][k]; \
            ACC.x += g4.x*w0.x; ACC.y += g4.x*w0.y; ACC.z += g4.x*w0.z; ACC.w += g4.x*w0.w; \
            ACC.x += g4.y*w1.x; ACC.y += g4.y*w1.y; ACC.z += g4.y*w1.z; ACC.w += g4.y*w1.w; \
            ACC.x += g4.z*w2.x; ACC.y += g4.z*w2.y; ACC.z += g4.z*w2.z; ACC.w += g4.z*w2.w; \
            ACC.x += g4.w*w3.x; ACC.y += g4.w*w3.y; ACC.z += g4.w*w3.z; ACC.w += g4.w*w3.w; }
            ROW(0, acc0) ROW(1, acc1) ROW(2, acc2) ROW(3, acc3)
#undef ROW
        }
        float4 b = *(const float4*)&b1[4 * tc];
#define EPI(R, ACC) { \
            int r = 4 * tr + R; float s = sv[i0 + r]; float4 res = ACC; \
            hs[r][4 * tc + 0] = fmaxf(res.x + s * b.x, 0.f); \
            hs[r][4 * tc + 1] = fmaxf(res.y + s * b.y, 0.f); \
            hs[r][4 * tc + 2] = fmaxf(res.z + s * b.z, 0.f); \
            hs[r][4 * tc + 3] = fmaxf(res.w + s * b.w, 0.f); }
        EPI(0, acc0) EPI(1, acc1) EPI(2, acc2) EPI(3, acc3)
#undef EPI
    }
    __syncthreads();
    // ---- stage 2: 2 rows x 4 cols per thread over K=256 ----
    {
        int tc = t & 31, tr = t >> 5;
        float4 acc0 = {0,0,0,0}, acc1 = {0,0,0,0};
        const float* wp = W2 + 4 * tc;
        for (int k = 0; k < HID; k += 4) {
            float4 w0 = *(const float4*)&wp[(size_t)(k + 0) * F_OUT];
            float4 w1 = *(const float4*)&wp[(size_t)(k + 1) * F_OUT];
            float4 w2 = *(const float4*)&wp[(size_t)(k + 2) * F_OUT];
            float4 w3 = *(const float4*)&wp[(size_t)(k + 3) * F_OUT];
#define ROW(R, ACC) { \
            float4 g4 = *(const float4*)&hs[2 * tr + R][k]; \
            ACC.x += g4.x*w0.x; ACC.y += g4.x*w0.y; ACC.z += g4.x*w0.z; ACC.w += g4.x*w0.w; \
            ACC.x += g4.y*w1.x; ACC.y += g4.y*w1.y; ACC.z += g4.y*w1.z; ACC.w += g4.y*w1.w; \
            ACC.x += g4.z*w2.x; ACC.y += g4.z*w2.y; ACC.z += g4.z*w2.z; ACC.w += g4.z*w2.w; \
            ACC.x += g4.w*w3.x; ACC.y += g4.w*w3.y; ACC.z += g4.w*w3.z; ACC.w += g4.w*w3.w; }
            ROW(0, acc0) ROW(1, acc1)
#undef ROW
        }
        float4 b = *(const float4*)&b2[4 * tc];
#define EPI(R, ACC) { \
            int i = i0 + 2 * tr + R; float dd = dis[i]; float4 res = ACC; \
            bf4 o; o.a = __float2bfloat16(dd * (res.x + b.x)); o.b = __float2bfloat16(dd * (res.y + b.y)); \
            o.c = __float2bfloat16(dd * (res.z + b.z)); o.d = __float2bfloat16(dd * (res.w + b.w)); \
            *(bf4*)(M2ph + (size_t)i * F_OUT + 4 * tc) = o; }
        EPI(0, acc0) EPI(1, acc1)
#undef EPI
    }
}

// ---------------------------------------------------------------------------
// 6. wpool: out[g][c] += (1/cnt_g) * sum_{j in chunk q} u[j][g] * M2ph[j][c]
// ---------------------------------------------------------------------------
__global__ __launch_bounds__(128) void wpool(const float* __restrict__ u,
                                             const __hip_bfloat16* __restrict__ M2ph,
                                             const int* __restrict__ batch,
                                             float* __restrict__ out) {
    int g = blockIdx.x, q = blockIdx.y, c = threadIdx.x;
    int j0 = q * (N_NODES / NQ);
    const unsigned short* Mu = (const unsigned short*)M2ph;
    __shared__ float us[N_NODES / NQ];   // 256
    us[c]       = u[(size_t)(j0 + c) * N_GRAPHS + g];
    us[c + 128] = u[(size_t)(j0 + c + 128) * N_GRAPHS + g];
    __syncthreads();
    float a0 = 0.f, a1 = 0.f, a2 = 0.f, a3 = 0.f, a4 = 0.f, a5 = 0.f, a6 = 0.f, a7 = 0.f;
    for (int jj = 0; jj < N_NODES / NQ; jj += 8) {
#define TERM(Q, ACC) ACC += us[jj + Q] * __uint_as_float((unsigned)Mu[(size_t)(j0 + jj + Q) * F_OUT + c] << 16);
        TERM(0, a0) TERM(1, a1) TERM(2, a2) TERM(3, a3)
        TERM(4, a4) TERM(5, a5) TERM(6, a6) TERM(7, a7)
#undef TERM
    }
    float s = ((a0 + a1) + (a2 + a3)) + ((a4 + a5) + (a6 + a7));
    // cnt_g via binary search on sorted batch
    int lo = 0, hi = N_NODES;
    while (lo < hi) { int m = (lo + hi) >> 1; if (batch[m] < g) lo = m + 1; else hi = m; }
    int start = lo;
    hi = N_NODES;
    while (lo < hi) { int m = (lo + hi) >> 1; if (batch[m] < g + 1) lo = m + 1; else hi = m; }
    int cnt = lo - start;
    atomicAdd(&out[(size_t)g * F_OUT + c], s / (float)(cnt > 0 ? cnt : 1));
}

// ---------------------------------------------------------------------------
extern "C" void kernel_launch(void* const* d_in, const int* in_sizes, int n_in,
                              void* d_out, int out_size, void* d_ws, size_t ws_size,
                              hipStream_t stream) {
    const float* X  = (const float*)d_in[0];
    const float* W1 = (const float*)d_in[1];
    const float* b1 = (const float*)d_in[2];
    const float* W2 = (const float*)d_in[3];
    const float* b2 = (const float*)d_in[4];
    const int* ei    = (const int*)d_in[5];
    const int* batch = (const int*)d_in[6];
    float* out = (float*)d_out;

    char* ws = (char*)d_ws;
    // [0, 8MB): mask during build. After spmm_scan2 (last mask reader), the
    // [2MB,4MB) slice is reused for M2ph (written by fused_gemm, stream-
    // ordered after spmm_scan2). u does NOT alias mask: it sits after G/Xh.
    unsigned int* mask   = (unsigned int*)(ws);
    __hip_bfloat16* M2ph = (__hip_bfloat16*)(ws + 2097152); // 2 MB (8192x128)
    float* G   = (float*)(ws + 8388608);                    // 4 MB (8192x128 f32)
    __hip_bfloat16* Xh = (__hip_bfloat16*)(ws + 12582912);  // 2 MB (8192x128 bf16)
    float* u   = (float*)(ws + 14680064);                   // 2 MB (8192x64)
    float* dis = (float*)(ws + 30441472);                   // 32 KB
    float* sv  = (float*)(ws + 30474240);                   // 32 KB

    cast_zero<<<3072, 256, 0, stream>>>(X, Xh, mask);
    scatter_edges<<<N_EDGES / 512, 256, 0, stream>>>(ei, mask);
    compute_dis<<<N_NODES / 4, 256, 0, stream>>>(mask, dis);
    spmm_scan2<<<N_NODES / 2, 256, 0, stream>>>(mask, Xh, dis, batch, G, sv, u);
    fused_gemm<<<N_NODES / 16, 256, 0, stream>>>(G, W1, b1, sv, W2, b2, dis, M2ph, out);
    wpool<<<dim3(N_GRAPHS, NQ), 128, 0, stream>>>(u, M2ph, batch, out);
}